// Round 6
// baseline (192.689 us; speedup 1.0000x reference)
//
#include <hip/hip_runtime.h>

// Problem constants: B=4, T=512, U=100, D=512, C=1024
constexpr int B_ = 4;
constexpr int T_ = 512;
constexpr int U_ = 100;
constexpr int D_ = 512;
constexpr int C_ = 1024;

typedef short  s16x8 __attribute__((ext_vector_type(8)));
typedef float  f32x4 __attribute__((ext_vector_type(4)));
typedef unsigned short u16x8 __attribute__((ext_vector_type(8)));

// fp32 -> bf16 RNE (finite inputs; no NaN handling needed)
__device__ __forceinline__ unsigned short f2bf(float f) {
    unsigned int u = __float_as_uint(f);
    return (unsigned short)((u + 0x7FFFu + ((u >> 16) & 1u)) >> 16);
}

// ---------------------------------------------------------------------------
// Fused projections via bf16 MFMA (unchanged since R3: passed, absmax 0.031).
// P[m,c] = sum_d A[m,d] * W[c, woff+d].  grid.y 0..15 -> enc, 16..19 -> dec.
// 128x128 tile, BK=32, 4 waves (2x2), 64x64 per wave = 4x4 fragments.
// ---------------------------------------------------------------------------
__global__ __launch_bounds__(256) void proj_gemm_mfma(
    const float* __restrict__ enc, const float* __restrict__ dec,
    const float* __restrict__ W, float* __restrict__ ep, float* __restrict__ dp)
{
    constexpr int BK  = 32;
    constexpr int LDK = 40;                 // 32 + 8 pad (80 B pitch)
    __shared__ unsigned short As[128 * LDK];
    __shared__ unsigned short Bs[128 * LDK];

    const int by = blockIdx.y;
    const bool is_enc = (by < 16);
    const float* __restrict__ A = is_enc ? enc : dec;
    float* __restrict__ P       = is_enc ? ep : dp;
    const int M    = is_enc ? (B_ * T_) : (B_ * U_);
    const int m0   = (is_enc ? by : (by - 16)) * 128;
    const int woff = is_enc ? 0 : D_;
    const int bn   = blockIdx.x * 128;

    const int tid  = threadIdx.x;
    const int lane = tid & 63;
    const int w    = tid >> 6;
    const int wm   = w >> 1;
    const int wn   = w & 1;
    const int lr   = lane & 15;
    const int lk   = lane >> 4;

    const int srow  = tid >> 1;
    const int shalf = tid & 1;

    f32x4 acc[4][4] = {};

    const float* __restrict__ aBase = A + (size_t)(m0 + srow) * D_ + shalf * 16;
    const float* __restrict__ wBase = W + (size_t)(bn + srow) * (2 * D_) + woff + shalf * 16;
    const bool arow_ok = (m0 + srow) < M;

    for (int kt = 0; kt < D_ / BK; ++kt) {
        if (kt) __syncthreads();
        const int k0 = kt * BK;

        {
            u16x8 v0 = {}, v1 = {};
            if (arow_ok) {
                const float4 f0 = *reinterpret_cast<const float4*>(aBase + k0 + 0);
                const float4 f1 = *reinterpret_cast<const float4*>(aBase + k0 + 4);
                const float4 f2 = *reinterpret_cast<const float4*>(aBase + k0 + 8);
                const float4 f3 = *reinterpret_cast<const float4*>(aBase + k0 + 12);
                v0 = u16x8{f2bf(f0.x), f2bf(f0.y), f2bf(f0.z), f2bf(f0.w),
                           f2bf(f1.x), f2bf(f1.y), f2bf(f1.z), f2bf(f1.w)};
                v1 = u16x8{f2bf(f2.x), f2bf(f2.y), f2bf(f2.z), f2bf(f2.w),
                           f2bf(f3.x), f2bf(f3.y), f2bf(f3.z), f2bf(f3.w)};
            }
            unsigned short* d = &As[srow * LDK + shalf * 16];
            *reinterpret_cast<u16x8*>(d)     = v0;
            *reinterpret_cast<u16x8*>(d + 8) = v1;
        }
        {
            const float4 f0 = *reinterpret_cast<const float4*>(wBase + k0 + 0);
            const float4 f1 = *reinterpret_cast<const float4*>(wBase + k0 + 4);
            const float4 f2 = *reinterpret_cast<const float4*>(wBase + k0 + 8);
            const float4 f3 = *reinterpret_cast<const float4*>(wBase + k0 + 12);
            const u16x8 v0 = {f2bf(f0.x), f2bf(f0.y), f2bf(f0.z), f2bf(f0.w),
                              f2bf(f1.x), f2bf(f1.y), f2bf(f1.z), f2bf(f1.w)};
            const u16x8 v1 = {f2bf(f2.x), f2bf(f2.y), f2bf(f2.z), f2bf(f2.w),
                              f2bf(f3.x), f2bf(f3.y), f2bf(f3.z), f2bf(f3.w)};
            unsigned short* d = &Bs[srow * LDK + shalf * 16];
            *reinterpret_cast<u16x8*>(d)     = v0;
            *reinterpret_cast<u16x8*>(d + 8) = v1;
        }
        __syncthreads();

        s16x8 afrag[4];
        #pragma unroll
        for (int fm = 0; fm < 4; ++fm)
            afrag[fm] = *reinterpret_cast<const s16x8*>(
                &As[(wm * 64 + fm * 16 + lr) * LDK + lk * 8]);
        #pragma unroll
        for (int fn = 0; fn < 4; ++fn) {
            const s16x8 bfrag = *reinterpret_cast<const s16x8*>(
                &Bs[(wn * 64 + fn * 16 + lr) * LDK + lk * 8]);
            #pragma unroll
            for (int fm = 0; fm < 4; ++fm)
                acc[fm][fn] = __builtin_amdgcn_mfma_f32_16x16x32_bf16(
                    afrag[fm], bfrag, acc[fm][fn], 0, 0, 0);
        }
    }

    #pragma unroll
    for (int fm = 0; fm < 4; ++fm) {
        #pragma unroll
        for (int r = 0; r < 4; ++r) {
            const int gm = m0 + wm * 64 + fm * 16 + lk * 4 + r;
            if (gm < M) {
                #pragma unroll
                for (int fn = 0; fn < 4; ++fn) {
                    const int c = bn + wn * 64 + fn * 16 + lr;
                    P[(size_t)gm * C_ + c] = acc[fm][fn][r];
                }
            }
        }
    }
}

// ---------------------------------------------------------------------------
// Phase 2, one block per bt row (R6): block writes its ENTIRE 400 KB output
// row sequentially (10x longer burst than R4's 40 KB blocks -> better HBM
// page locality), reads its ep row exactly ONCE (no cross-block ep reuse
// needed at all), and dp is a 400 KB-per-XCD L2-resident set (chunked
// swizzle gives each XCD exactly one b). NT stores kept (proven best in
// R3/R4; keeps L2 clean for dp). No double-buffering: at >80% BW util,
// TLP (32 waves/CU at low VGPR) hides L2-hit latency.
// ---------------------------------------------------------------------------
constexpr int NBT  = B_ * T_;   // 2048 blocks, divisible by 8
constexpr int NXCD = 8;

__global__ __launch_bounds__(256) void bcast_add_bt(
    const float* __restrict__ ep, const float* __restrict__ dp,
    float* __restrict__ out)
{
    const int bid = blockIdx.x;
    // chunked XCD swizzle (bijective: NBT % 8 == 0); XCD n owns bt range
    // [n*256, (n+1)*256) -> exactly one b per XCD -> dp slice 400 KB.
    const int bt  = (bid & (NXCD - 1)) * (NBT / NXCD) + (bid >> 3);
    const int b   = bt / T_;

    const int coff = threadIdx.x * 4;

    const f32x4 e = *reinterpret_cast<const f32x4*>(&ep[(size_t)bt * C_ + coff]);

    const float* __restrict__ dpb = dp + (size_t)b * U_ * C_ + coff;
    float* __restrict__ outp = out + (size_t)bt * U_ * C_ + coff;

    #pragma unroll 1
    for (int g = 0; g < U_ / 10; ++g) {
        f32x4 d[10];
        #pragma unroll
        for (int j = 0; j < 10; ++j)
            d[j] = *reinterpret_cast<const f32x4*>(dpb + (size_t)(g * 10 + j) * C_);
        #pragma unroll
        for (int j = 0; j < 10; ++j) {
            const f32x4 r = e + d[j];
            __builtin_nontemporal_store(
                r, reinterpret_cast<f32x4*>(outp + (size_t)(g * 10 + j) * C_));
        }
    }
}

extern "C" void kernel_launch(void* const* d_in, const int* in_sizes, int n_in,
                              void* d_out, int out_size, void* d_ws, size_t ws_size,
                              hipStream_t stream)
{
    const float* enc = (const float*)d_in[0];   // (B, T, D)
    const float* dec = (const float*)d_in[1];   // (B, U, D)
    const float* W   = (const float*)d_in[2];   // (C, 2D)
    float* out = (float*)d_out;                 // (B, T, U, C) fp32

    const int Menc = B_ * T_;   // 2048
    const int Mdec = B_ * U_;   // 400

    const size_t need = (size_t)(Menc + Mdec) * C_ * sizeof(float);  // ~9.6 MB
    if (ws_size < need) return;

    float* ep = (float*)d_ws;
    float* dp = ep + (size_t)Menc * C_;

    // Phase 1: both projections in ONE launch (enc: by 0..15, dec: by 16..19)
    proj_gemm_mfma<<<dim3(C_ / 128, 20), 256, 0, stream>>>(enc, dec, W, ep, dp);

    // Phase 2: broadcast add, one block per bt row, XCD-swizzled, NT stores
    bcast_add_bt<<<NBT, 256, 0, stream>>>(ep, dp, out);
}

// Round 7
// 178.327 us; speedup vs baseline: 1.0805x; 1.0805x over previous
//
#include <hip/hip_runtime.h>

// Problem constants: B=4, T=512, U=100, D=512, C=1024
constexpr int B_ = 4;
constexpr int T_ = 512;
constexpr int U_ = 100;
constexpr int D_ = 512;
constexpr int C_ = 1024;

typedef short  s16x8 __attribute__((ext_vector_type(8)));
typedef float  f32x4 __attribute__((ext_vector_type(4)));
typedef unsigned short u16x8 __attribute__((ext_vector_type(8)));

// fp32 -> bf16 RNE (finite inputs; no NaN handling needed)
__device__ __forceinline__ unsigned short f2bf(float f) {
    unsigned int u = __float_as_uint(f);
    return (unsigned short)((u + 0x7FFFu + ((u >> 16) & 1u)) >> 16);
}

// ---------------------------------------------------------------------------
// Fused projections via bf16 MFMA (unchanged since R3: passed, absmax 0.031).
// P[m,c] = sum_d A[m,d] * W[c, woff+d].  grid.y 0..15 -> enc, 16..19 -> dec.
// 128x128 tile, BK=32, 4 waves (2x2), 64x64 per wave = 4x4 fragments.
// ---------------------------------------------------------------------------
__global__ __launch_bounds__(256) void proj_gemm_mfma(
    const float* __restrict__ enc, const float* __restrict__ dec,
    const float* __restrict__ W, float* __restrict__ ep, float* __restrict__ dp)
{
    constexpr int BK  = 32;
    constexpr int LDK = 40;                 // 32 + 8 pad (80 B pitch)
    __shared__ unsigned short As[128 * LDK];
    __shared__ unsigned short Bs[128 * LDK];

    const int by = blockIdx.y;
    const bool is_enc = (by < 16);
    const float* __restrict__ A = is_enc ? enc : dec;
    float* __restrict__ P       = is_enc ? ep : dp;
    const int M    = is_enc ? (B_ * T_) : (B_ * U_);
    const int m0   = (is_enc ? by : (by - 16)) * 128;
    const int woff = is_enc ? 0 : D_;
    const int bn   = blockIdx.x * 128;

    const int tid  = threadIdx.x;
    const int lane = tid & 63;
    const int w    = tid >> 6;
    const int wm   = w >> 1;
    const int wn   = w & 1;
    const int lr   = lane & 15;
    const int lk   = lane >> 4;

    const int srow  = tid >> 1;
    const int shalf = tid & 1;

    f32x4 acc[4][4] = {};

    const float* __restrict__ aBase = A + (size_t)(m0 + srow) * D_ + shalf * 16;
    const float* __restrict__ wBase = W + (size_t)(bn + srow) * (2 * D_) + woff + shalf * 16;
    const bool arow_ok = (m0 + srow) < M;

    for (int kt = 0; kt < D_ / BK; ++kt) {
        if (kt) __syncthreads();
        const int k0 = kt * BK;

        {
            u16x8 v0 = {}, v1 = {};
            if (arow_ok) {
                const float4 f0 = *reinterpret_cast<const float4*>(aBase + k0 + 0);
                const float4 f1 = *reinterpret_cast<const float4*>(aBase + k0 + 4);
                const float4 f2 = *reinterpret_cast<const float4*>(aBase + k0 + 8);
                const float4 f3 = *reinterpret_cast<const float4*>(aBase + k0 + 12);
                v0 = u16x8{f2bf(f0.x), f2bf(f0.y), f2bf(f0.z), f2bf(f0.w),
                           f2bf(f1.x), f2bf(f1.y), f2bf(f1.z), f2bf(f1.w)};
                v1 = u16x8{f2bf(f2.x), f2bf(f2.y), f2bf(f2.z), f2bf(f2.w),
                           f2bf(f3.x), f2bf(f3.y), f2bf(f3.z), f2bf(f3.w)};
            }
            unsigned short* d = &As[srow * LDK + shalf * 16];
            *reinterpret_cast<u16x8*>(d)     = v0;
            *reinterpret_cast<u16x8*>(d + 8) = v1;
        }
        {
            const float4 f0 = *reinterpret_cast<const float4*>(wBase + k0 + 0);
            const float4 f1 = *reinterpret_cast<const float4*>(wBase + k0 + 4);
            const float4 f2 = *reinterpret_cast<const float4*>(wBase + k0 + 8);
            const float4 f3 = *reinterpret_cast<const float4*>(wBase + k0 + 12);
            const u16x8 v0 = {f2bf(f0.x), f2bf(f0.y), f2bf(f0.z), f2bf(f0.w),
                              f2bf(f1.x), f2bf(f1.y), f2bf(f1.z), f2bf(f1.w)};
            const u16x8 v1 = {f2bf(f2.x), f2bf(f2.y), f2bf(f2.z), f2bf(f2.w),
                              f2bf(f3.x), f2bf(f3.y), f2bf(f3.z), f2bf(f3.w)};
            unsigned short* d = &Bs[srow * LDK + shalf * 16];
            *reinterpret_cast<u16x8*>(d)     = v0;
            *reinterpret_cast<u16x8*>(d + 8) = v1;
        }
        __syncthreads();

        s16x8 afrag[4];
        #pragma unroll
        for (int fm = 0; fm < 4; ++fm)
            afrag[fm] = *reinterpret_cast<const s16x8*>(
                &As[(wm * 64 + fm * 16 + lr) * LDK + lk * 8]);
        #pragma unroll
        for (int fn = 0; fn < 4; ++fn) {
            const s16x8 bfrag = *reinterpret_cast<const s16x8*>(
                &Bs[(wn * 64 + fn * 16 + lr) * LDK + lk * 8]);
            #pragma unroll
            for (int fm = 0; fm < 4; ++fm)
                acc[fm][fn] = __builtin_amdgcn_mfma_f32_16x16x32_bf16(
                    afrag[fm], bfrag, acc[fm][fn], 0, 0, 0);
        }
    }

    #pragma unroll
    for (int fm = 0; fm < 4; ++fm) {
        #pragma unroll
        for (int r = 0; r < 4; ++r) {
            const int gm = m0 + wm * 64 + fm * 16 + lk * 4 + r;
            if (gm < M) {
                #pragma unroll
                for (int fn = 0; fn < 4; ++fn) {
                    const int c = bn + wn * 64 + fn * 16 + lr;
                    P[(size_t)gm * C_ + c] = acc[fm][fn][r];
                }
            }
        }
    }
}

// ---------------------------------------------------------------------------
// Phase 2 — EXACT R4 structure (best so far: 169.5 us), single variable
// flipped: PLAIN stores instead of nontemporal. A/B isolates store policy:
//   theory (a) NT protects dp/ep L2 residency  -> this regresses (~175-185)
//   theory (b) NT forfeits the plain-store 6.7 TB/s write path -> ~150-158
// 1D block = one (b,t) x 10 u's x full C; 20480 short-lived blocks; chunked
// XCD swizzle so each XCD reads a private 1 MB ep slice + 400 KB dp slice.
// ---------------------------------------------------------------------------
constexpr int UT_  = 10;
constexpr int NBLK = B_ * T_ * (U_ / UT_);   // 20480, divisible by 8
constexpr int NXCD = 8;

__global__ __launch_bounds__(256) void bcast_add(
    const float* __restrict__ ep, const float* __restrict__ dp,
    float* __restrict__ out)
{
    // chunked XCD swizzle (bijective: NBLK % 8 == 0)
    const int bid  = blockIdx.x;
    const int lbid = (bid & (NXCD - 1)) * (NBLK / NXCD) + (bid >> 3);

    const int ug  = lbid % (U_ / UT_);
    const int bt  = lbid / (U_ / UT_);
    const int b   = bt / T_;
    const int tid = threadIdx.x;
    const int coff = tid * 4;

    const f32x4 e = *reinterpret_cast<const f32x4*>(&ep[(size_t)bt * C_ + coff]);

    const float* dpr = dp + (size_t)(b * U_ + ug * UT_) * C_ + coff;
    float* outp = out + ((size_t)bt * U_ + ug * UT_) * C_ + coff;

    // load all dp rows first (independent -> all in flight), then add+store
    f32x4 d[UT_];
    #pragma unroll
    for (int i = 0; i < UT_; ++i)
        d[i] = *reinterpret_cast<const f32x4*>(dpr + (size_t)i * C_);

    #pragma unroll
    for (int i = 0; i < UT_; ++i) {
        const f32x4 r = e + d[i];
        *reinterpret_cast<f32x4*>(outp + (size_t)i * C_) = r;   // PLAIN store
    }
}

extern "C" void kernel_launch(void* const* d_in, const int* in_sizes, int n_in,
                              void* d_out, int out_size, void* d_ws, size_t ws_size,
                              hipStream_t stream)
{
    const float* enc = (const float*)d_in[0];   // (B, T, D)
    const float* dec = (const float*)d_in[1];   // (B, U, D)
    const float* W   = (const float*)d_in[2];   // (C, 2D)
    float* out = (float*)d_out;                 // (B, T, U, C) fp32

    const int Menc = B_ * T_;   // 2048
    const int Mdec = B_ * U_;   // 400

    const size_t need = (size_t)(Menc + Mdec) * C_ * sizeof(float);  // ~9.6 MB
    if (ws_size < need) return;

    float* ep = (float*)d_ws;
    float* dp = ep + (size_t)Menc * C_;

    // Phase 1: both projections in ONE launch (enc: by 0..15, dec: by 16..19)
    proj_gemm_mfma<<<dim3(C_ / 128, 20), 256, 0, stream>>>(enc, dec, W, ep, dp);

    // Phase 2: broadcast add (HBM write-bound bulk), R4 structure, plain stores
    bcast_add<<<NBLK, 256, 0, stream>>>(ep, dp, out);
}

// Round 8
// 164.470 us; speedup vs baseline: 1.1716x; 1.0843x over previous
//
#include <hip/hip_runtime.h>

// Problem constants: B=4, T=512, U=100, D=512, C=1024
constexpr int B_ = 4;
constexpr int T_ = 512;
constexpr int U_ = 100;
constexpr int D_ = 512;
constexpr int C_ = 1024;

typedef short  s16x8 __attribute__((ext_vector_type(8)));
typedef float  f32x4 __attribute__((ext_vector_type(4)));
typedef unsigned short u16x8 __attribute__((ext_vector_type(8)));

// fp32 -> bf16 RNE (finite inputs; no NaN handling needed)
__device__ __forceinline__ unsigned short f2bf(float f) {
    unsigned int u = __float_as_uint(f);
    return (unsigned short)((u + 0x7FFFu + ((u >> 16) & 1u)) >> 16);
}

// ---------------------------------------------------------------------------
// Fused projections via bf16 MFMA — R8: 64x64 tiles for CU occupancy.
// R3-R7 used 128x128 -> only 160 blocks on 256 CUs (96 idle), ~10 us phase.
// 64x64 -> 624 blocks, >=2 co-resident/CU (LDS 20 KB), per-block critical
// path 1/4 -> predicted ~4-5 us. Same LDS layout (LDK=40 pad), same MFMA,
// same epilogue mapping; only tile geometry changes.
// grid.y 0..31 -> enc (M=2048), 32..38 -> dec (M=400, guarded).
// ---------------------------------------------------------------------------
__global__ __launch_bounds__(256) void proj_gemm_mfma(
    const float* __restrict__ enc, const float* __restrict__ dec,
    const float* __restrict__ W, float* __restrict__ ep, float* __restrict__ dp)
{
    constexpr int BK  = 32;
    constexpr int LDK = 40;                 // 32 + 8 pad (80 B pitch)
    __shared__ unsigned short As[64 * LDK];
    __shared__ unsigned short Bs[64 * LDK];

    const int by = blockIdx.y;
    const bool is_enc = (by < 32);
    const float* __restrict__ A = is_enc ? enc : dec;
    float* __restrict__ P       = is_enc ? ep : dp;
    const int M    = is_enc ? (B_ * T_) : (B_ * U_);
    const int m0   = (is_enc ? by : (by - 32)) * 64;
    const int woff = is_enc ? 0 : D_;
    const int bn   = blockIdx.x * 64;

    const int tid  = threadIdx.x;
    const int lane = tid & 63;
    const int w    = tid >> 6;              // wave 0..3
    const int wm   = w >> 1;                // 0..1 (m half)
    const int wn   = w & 1;                 // 0..1 (n half)
    const int lr   = lane & 15;
    const int lk   = lane >> 4;             // 0..3

    // staging: 4 threads per row, 8 k-floats each
    const int srow = tid >> 2;              // 0..63
    const int sq   = tid & 3;               // k-offset 8*sq

    f32x4 acc[2][2] = {};

    const float* __restrict__ aBase = A + (size_t)(m0 + srow) * D_ + sq * 8;
    const float* __restrict__ wBase = W + (size_t)(bn + srow) * (2 * D_) + woff + sq * 8;
    const bool arow_ok = (m0 + srow) < M;

    for (int kt = 0; kt < D_ / BK; ++kt) {
        if (kt) __syncthreads();
        const int k0 = kt * BK;

        {   // stage A (guarded)
            u16x8 v = {};
            if (arow_ok) {
                const float4 f0 = *reinterpret_cast<const float4*>(aBase + k0 + 0);
                const float4 f1 = *reinterpret_cast<const float4*>(aBase + k0 + 4);
                v = u16x8{f2bf(f0.x), f2bf(f0.y), f2bf(f0.z), f2bf(f0.w),
                          f2bf(f1.x), f2bf(f1.y), f2bf(f1.z), f2bf(f1.w)};
            }
            *reinterpret_cast<u16x8*>(&As[srow * LDK + sq * 8]) = v;
        }
        {   // stage B (W rows always in range: bn+srow < 1024)
            const float4 f0 = *reinterpret_cast<const float4*>(wBase + k0 + 0);
            const float4 f1 = *reinterpret_cast<const float4*>(wBase + k0 + 4);
            const u16x8 v = {f2bf(f0.x), f2bf(f0.y), f2bf(f0.z), f2bf(f0.w),
                             f2bf(f1.x), f2bf(f1.y), f2bf(f1.z), f2bf(f1.w)};
            *reinterpret_cast<u16x8*>(&Bs[srow * LDK + sq * 8]) = v;
        }
        __syncthreads();

        s16x8 afrag[2];
        #pragma unroll
        for (int fm = 0; fm < 2; ++fm)
            afrag[fm] = *reinterpret_cast<const s16x8*>(
                &As[(wm * 32 + fm * 16 + lr) * LDK + lk * 8]);
        #pragma unroll
        for (int fn = 0; fn < 2; ++fn) {
            const s16x8 bfrag = *reinterpret_cast<const s16x8*>(
                &Bs[(wn * 32 + fn * 16 + lr) * LDK + lk * 8]);
            #pragma unroll
            for (int fm = 0; fm < 2; ++fm)
                acc[fm][fn] = __builtin_amdgcn_mfma_f32_16x16x32_bf16(
                    afrag[fm], bfrag, acc[fm][fn], 0, 0, 0);
        }
    }

    // epilogue: C/D layout col=lane&15, row=(lane>>4)*4+r
    #pragma unroll
    for (int fm = 0; fm < 2; ++fm) {
        #pragma unroll
        for (int r = 0; r < 4; ++r) {
            const int gm = m0 + wm * 32 + fm * 16 + lk * 4 + r;
            if (gm < M) {
                #pragma unroll
                for (int fn = 0; fn < 2; ++fn) {
                    const int c = bn + wn * 32 + fn * 16 + lr;
                    P[(size_t)gm * C_ + c] = acc[fm][fn][r];
                }
            }
        }
    }
}

// ---------------------------------------------------------------------------
// Phase 2 — byte-exact R4 bcast (best: 169.5 us). NT stores CONFIRMED best
// by R7 A/B (plain = +9 us: write stream evicts dp/ep from L2; NT's ~5.4
// TB/s is the better net). 1D block = one (b,t) x 10 u's x full C; 20480
// short-lived blocks; chunked XCD swizzle -> each XCD reads a private 1 MB
// ep slice + 400 KB dp slice, L2-resident under NT writes.
// ---------------------------------------------------------------------------
constexpr int UT_  = 10;
constexpr int NBLK = B_ * T_ * (U_ / UT_);   // 20480, divisible by 8
constexpr int NXCD = 8;

__global__ __launch_bounds__(256) void bcast_add(
    const float* __restrict__ ep, const float* __restrict__ dp,
    float* __restrict__ out)
{
    // chunked XCD swizzle (bijective: NBLK % 8 == 0)
    const int bid  = blockIdx.x;
    const int lbid = (bid & (NXCD - 1)) * (NBLK / NXCD) + (bid >> 3);

    const int ug  = lbid % (U_ / UT_);
    const int bt  = lbid / (U_ / UT_);
    const int b   = bt / T_;
    const int tid = threadIdx.x;
    const int coff = tid * 4;

    const f32x4 e = *reinterpret_cast<const f32x4*>(&ep[(size_t)bt * C_ + coff]);

    const float* dpr = dp + (size_t)(b * U_ + ug * UT_) * C_ + coff;
    float* outp = out + ((size_t)bt * U_ + ug * UT_) * C_ + coff;

    // load all dp rows first (independent -> all in flight), then add+store
    f32x4 d[UT_];
    #pragma unroll
    for (int i = 0; i < UT_; ++i)
        d[i] = *reinterpret_cast<const f32x4*>(dpr + (size_t)i * C_);

    #pragma unroll
    for (int i = 0; i < UT_; ++i) {
        const f32x4 r = e + d[i];
        __builtin_nontemporal_store(r, reinterpret_cast<f32x4*>(outp + (size_t)i * C_));
    }
}

extern "C" void kernel_launch(void* const* d_in, const int* in_sizes, int n_in,
                              void* d_out, int out_size, void* d_ws, size_t ws_size,
                              hipStream_t stream)
{
    const float* enc = (const float*)d_in[0];   // (B, T, D)
    const float* dec = (const float*)d_in[1];   // (B, U, D)
    const float* W   = (const float*)d_in[2];   // (C, 2D)
    float* out = (float*)d_out;                 // (B, T, U, C) fp32

    const int Menc = B_ * T_;   // 2048
    const int Mdec = B_ * U_;   // 400

    const size_t need = (size_t)(Menc + Mdec) * C_ * sizeof(float);  // ~9.6 MB
    if (ws_size < need) return;

    float* ep = (float*)d_ws;
    float* dp = ep + (size_t)Menc * C_;

    // Phase 1: both projections, 64x64 tiles -> 624 blocks (>=2/CU)
    // grid.y: enc 0..31 (2048/64), dec 32..38 (ceil(400/64)=7)
    proj_gemm_mfma<<<dim3(C_ / 64, 32 + 7), 256, 0, stream>>>(enc, dec, W, ep, dp);

    // Phase 2: broadcast add — byte-exact R4 (NT + chunked XCD swizzle)
    bcast_add<<<NBLK, 256, 0, stream>>>(ep, dp, out);
}

// Round 9
// 162.335 us; speedup vs baseline: 1.1870x; 1.0131x over previous
//
#include <hip/hip_runtime.h>

// Problem constants: B=4, T=512, U=100, D=512, C=1024
constexpr int B_ = 4;
constexpr int T_ = 512;
constexpr int U_ = 100;
constexpr int D_ = 512;
constexpr int C_ = 1024;

typedef short  s16x8 __attribute__((ext_vector_type(8)));
typedef float  f32x4 __attribute__((ext_vector_type(4)));
typedef unsigned short u16x8 __attribute__((ext_vector_type(8)));

// fp32 -> bf16 RNE (finite inputs; no NaN handling needed)
__device__ __forceinline__ unsigned short f2bf(float f) {
    unsigned int u = __float_as_uint(f);
    return (unsigned short)((u + 0x7FFFu + ((u >> 16) & 1u)) >> 16);
}

// ---------------------------------------------------------------------------
// Fused projections via bf16 MFMA — 64x64 tiles (R8-confirmed: 624 blocks,
// >=2 co-resident/CU, ~5 us). grid.y 0..31 -> enc, 32..38 -> dec (guarded).
// ---------------------------------------------------------------------------
__global__ __launch_bounds__(256) void proj_gemm_mfma(
    const float* __restrict__ enc, const float* __restrict__ dec,
    const float* __restrict__ W, float* __restrict__ ep, float* __restrict__ dp)
{
    constexpr int BK  = 32;
    constexpr int LDK = 40;                 // 32 + 8 pad (80 B pitch)
    __shared__ unsigned short As[64 * LDK];
    __shared__ unsigned short Bs[64 * LDK];

    const int by = blockIdx.y;
    const bool is_enc = (by < 32);
    const float* __restrict__ A = is_enc ? enc : dec;
    float* __restrict__ P       = is_enc ? ep : dp;
    const int M    = is_enc ? (B_ * T_) : (B_ * U_);
    const int m0   = (is_enc ? by : (by - 32)) * 64;
    const int woff = is_enc ? 0 : D_;
    const int bn   = blockIdx.x * 64;

    const int tid  = threadIdx.x;
    const int lane = tid & 63;
    const int w    = tid >> 6;              // wave 0..3
    const int wm   = w >> 1;                // 0..1 (m half)
    const int wn   = w & 1;                 // 0..1 (n half)
    const int lr   = lane & 15;
    const int lk   = lane >> 4;             // 0..3

    // staging: 4 threads per row, 8 k-floats each
    const int srow = tid >> 2;              // 0..63
    const int sq   = tid & 3;               // k-offset 8*sq

    f32x4 acc[2][2] = {};

    const float* __restrict__ aBase = A + (size_t)(m0 + srow) * D_ + sq * 8;
    const float* __restrict__ wBase = W + (size_t)(bn + srow) * (2 * D_) + woff + sq * 8;
    const bool arow_ok = (m0 + srow) < M;

    for (int kt = 0; kt < D_ / BK; ++kt) {
        if (kt) __syncthreads();
        const int k0 = kt * BK;

        {   // stage A (guarded)
            u16x8 v = {};
            if (arow_ok) {
                const float4 f0 = *reinterpret_cast<const float4*>(aBase + k0 + 0);
                const float4 f1 = *reinterpret_cast<const float4*>(aBase + k0 + 4);
                v = u16x8{f2bf(f0.x), f2bf(f0.y), f2bf(f0.z), f2bf(f0.w),
                          f2bf(f1.x), f2bf(f1.y), f2bf(f1.z), f2bf(f1.w)};
            }
            *reinterpret_cast<u16x8*>(&As[srow * LDK + sq * 8]) = v;
        }
        {   // stage B (W rows always in range: bn+srow < 1024)
            const float4 f0 = *reinterpret_cast<const float4*>(wBase + k0 + 0);
            const float4 f1 = *reinterpret_cast<const float4*>(wBase + k0 + 4);
            const u16x8 v = {f2bf(f0.x), f2bf(f0.y), f2bf(f0.z), f2bf(f0.w),
                             f2bf(f1.x), f2bf(f1.y), f2bf(f1.z), f2bf(f1.w)};
            *reinterpret_cast<u16x8*>(&Bs[srow * LDK + sq * 8]) = v;
        }
        __syncthreads();

        s16x8 afrag[2];
        #pragma unroll
        for (int fm = 0; fm < 2; ++fm)
            afrag[fm] = *reinterpret_cast<const s16x8*>(
                &As[(wm * 32 + fm * 16 + lr) * LDK + lk * 8]);
        #pragma unroll
        for (int fn = 0; fn < 2; ++fn) {
            const s16x8 bfrag = *reinterpret_cast<const s16x8*>(
                &Bs[(wn * 32 + fn * 16 + lr) * LDK + lk * 8]);
            #pragma unroll
            for (int fm = 0; fm < 2; ++fm)
                acc[fm][fn] = __builtin_amdgcn_mfma_f32_16x16x32_bf16(
                    afrag[fm], bfrag, acc[fm][fn], 0, 0, 0);
        }
    }

    // epilogue: C/D layout col=lane&15, row=(lane>>4)*4+r
    #pragma unroll
    for (int fm = 0; fm < 2; ++fm) {
        #pragma unroll
        for (int r = 0; r < 4; ++r) {
            const int gm = m0 + wm * 32 + fm * 16 + lk * 4 + r;
            if (gm < M) {
                #pragma unroll
                for (int fn = 0; fn < 2; ++fn) {
                    const int c = bn + wn * 32 + fn * 16 + lr;
                    P[(size_t)gm * C_ + c] = acc[fm][fn][r];
                }
            }
        }
    }
}

// ---------------------------------------------------------------------------
// Phase 2 — R4/R8 structure, single variable: UT 10 -> 5 (20 KB writes per
// block, 40960 blocks). Tests the UNTESTED downward granularity direction
// (40 KB best so far; 320 KB/400 KB worse). NT stores (R7 A/B-confirmed),
// chunked XCD swizzle (R4-confirmed). Decision rule: >=162 us -> axis
// exhausted, declare roofline next round.
// ---------------------------------------------------------------------------
constexpr int UT_  = 5;
constexpr int NBLK = B_ * T_ * (U_ / UT_);   // 40960, divisible by 8
constexpr int NXCD = 8;

__global__ __launch_bounds__(256) void bcast_add(
    const float* __restrict__ ep, const float* __restrict__ dp,
    float* __restrict__ out)
{
    // chunked XCD swizzle (bijective: NBLK % 8 == 0)
    const int bid  = blockIdx.x;
    const int lbid = (bid & (NXCD - 1)) * (NBLK / NXCD) + (bid >> 3);

    const int ug  = lbid % (U_ / UT_);
    const int bt  = lbid / (U_ / UT_);
    const int b   = bt / T_;
    const int tid = threadIdx.x;
    const int coff = tid * 4;

    const f32x4 e = *reinterpret_cast<const f32x4*>(&ep[(size_t)bt * C_ + coff]);

    const float* dpr = dp + (size_t)(b * U_ + ug * UT_) * C_ + coff;
    float* outp = out + ((size_t)bt * U_ + ug * UT_) * C_ + coff;

    // load all dp rows first (independent -> all in flight), then add+store
    f32x4 d[UT_];
    #pragma unroll
    for (int i = 0; i < UT_; ++i)
        d[i] = *reinterpret_cast<const f32x4*>(dpr + (size_t)i * C_);

    #pragma unroll
    for (int i = 0; i < UT_; ++i) {
        const f32x4 r = e + d[i];
        __builtin_nontemporal_store(r, reinterpret_cast<f32x4*>(outp + (size_t)i * C_));
    }
}

extern "C" void kernel_launch(void* const* d_in, const int* in_sizes, int n_in,
                              void* d_out, int out_size, void* d_ws, size_t ws_size,
                              hipStream_t stream)
{
    const float* enc = (const float*)d_in[0];   // (B, T, D)
    const float* dec = (const float*)d_in[1];   // (B, U, D)
    const float* W   = (const float*)d_in[2];   // (C, 2D)
    float* out = (float*)d_out;                 // (B, T, U, C) fp32

    const int Menc = B_ * T_;   // 2048
    const int Mdec = B_ * U_;   // 400

    const size_t need = (size_t)(Menc + Mdec) * C_ * sizeof(float);  // ~9.6 MB
    if (ws_size < need) return;

    float* ep = (float*)d_ws;
    float* dp = ep + (size_t)Menc * C_;

    // Phase 1: both projections, 64x64 tiles -> 624 blocks (>=2/CU)
    proj_gemm_mfma<<<dim3(C_ / 64, 32 + 7), 256, 0, stream>>>(enc, dec, W, ep, dp);

    // Phase 2: broadcast add — UT=5 granularity probe (NT + chunked swizzle)
    bcast_add<<<NBLK, 256, 0, stream>>>(ep, dp, out);
}

// Round 10
// 153.933 us; speedup vs baseline: 1.2518x; 1.0546x over previous
//
#include <hip/hip_runtime.h>

// Problem constants: B=4, T=512, U=100, D=512, C=1024
constexpr int B_ = 4;
constexpr int T_ = 512;
constexpr int U_ = 100;
constexpr int D_ = 512;
constexpr int C_ = 1024;

typedef short  s16x8 __attribute__((ext_vector_type(8)));
typedef float  f32x4 __attribute__((ext_vector_type(4)));
typedef unsigned short u16x8 __attribute__((ext_vector_type(8)));

// fp32 -> bf16 RNE (finite inputs; no NaN handling needed)
__device__ __forceinline__ unsigned short f2bf(float f) {
    unsigned int u = __float_as_uint(f);
    return (unsigned short)((u + 0x7FFFu + ((u >> 16) & 1u)) >> 16);
}

// ---------------------------------------------------------------------------
// Fused projections via bf16 MFMA — 64x64 tiles (R8-confirmed: 624 blocks,
// >=2 co-resident/CU, ~5 us). grid.y 0..31 -> enc, 32..38 -> dec (guarded).
// ---------------------------------------------------------------------------
__global__ __launch_bounds__(256) void proj_gemm_mfma(
    const float* __restrict__ enc, const float* __restrict__ dec,
    const float* __restrict__ W, float* __restrict__ ep, float* __restrict__ dp)
{
    constexpr int BK  = 32;
    constexpr int LDK = 40;                 // 32 + 8 pad (80 B pitch)
    __shared__ unsigned short As[64 * LDK];
    __shared__ unsigned short Bs[64 * LDK];

    const int by = blockIdx.y;
    const bool is_enc = (by < 32);
    const float* __restrict__ A = is_enc ? enc : dec;
    float* __restrict__ P       = is_enc ? ep : dp;
    const int M    = is_enc ? (B_ * T_) : (B_ * U_);
    const int m0   = (is_enc ? by : (by - 32)) * 64;
    const int woff = is_enc ? 0 : D_;
    const int bn   = blockIdx.x * 64;

    const int tid  = threadIdx.x;
    const int lane = tid & 63;
    const int w    = tid >> 6;              // wave 0..3
    const int wm   = w >> 1;                // 0..1 (m half)
    const int wn   = w & 1;                 // 0..1 (n half)
    const int lr   = lane & 15;
    const int lk   = lane >> 4;             // 0..3

    // staging: 4 threads per row, 8 k-floats each
    const int srow = tid >> 2;              // 0..63
    const int sq   = tid & 3;               // k-offset 8*sq

    f32x4 acc[2][2] = {};

    const float* __restrict__ aBase = A + (size_t)(m0 + srow) * D_ + sq * 8;
    const float* __restrict__ wBase = W + (size_t)(bn + srow) * (2 * D_) + woff + sq * 8;
    const bool arow_ok = (m0 + srow) < M;

    for (int kt = 0; kt < D_ / BK; ++kt) {
        if (kt) __syncthreads();
        const int k0 = kt * BK;

        {   // stage A (guarded)
            u16x8 v = {};
            if (arow_ok) {
                const float4 f0 = *reinterpret_cast<const float4*>(aBase + k0 + 0);
                const float4 f1 = *reinterpret_cast<const float4*>(aBase + k0 + 4);
                v = u16x8{f2bf(f0.x), f2bf(f0.y), f2bf(f0.z), f2bf(f0.w),
                          f2bf(f1.x), f2bf(f1.y), f2bf(f1.z), f2bf(f1.w)};
            }
            *reinterpret_cast<u16x8*>(&As[srow * LDK + sq * 8]) = v;
        }
        {   // stage B (W rows always in range: bn+srow < 1024)
            const float4 f0 = *reinterpret_cast<const float4*>(wBase + k0 + 0);
            const float4 f1 = *reinterpret_cast<const float4*>(wBase + k0 + 4);
            const u16x8 v = {f2bf(f0.x), f2bf(f0.y), f2bf(f0.z), f2bf(f0.w),
                             f2bf(f1.x), f2bf(f1.y), f2bf(f1.z), f2bf(f1.w)};
            *reinterpret_cast<u16x8*>(&Bs[srow * LDK + sq * 8]) = v;
        }
        __syncthreads();

        s16x8 afrag[2];
        #pragma unroll
        for (int fm = 0; fm < 2; ++fm)
            afrag[fm] = *reinterpret_cast<const s16x8*>(
                &As[(wm * 32 + fm * 16 + lr) * LDK + lk * 8]);
        #pragma unroll
        for (int fn = 0; fn < 2; ++fn) {
            const s16x8 bfrag = *reinterpret_cast<const s16x8*>(
                &Bs[(wn * 32 + fn * 16 + lr) * LDK + lk * 8]);
            #pragma unroll
            for (int fm = 0; fm < 2; ++fm)
                acc[fm][fn] = __builtin_amdgcn_mfma_f32_16x16x32_bf16(
                    afrag[fm], bfrag, acc[fm][fn], 0, 0, 0);
        }
    }

    // epilogue: C/D layout col=lane&15, row=(lane>>4)*4+r
    #pragma unroll
    for (int fm = 0; fm < 2; ++fm) {
        #pragma unroll
        for (int r = 0; r < 4; ++r) {
            const int gm = m0 + wm * 32 + fm * 16 + lk * 4 + r;
            if (gm < M) {
                #pragma unroll
                for (int fn = 0; fn < 2; ++fn) {
                    const int c = bn + wn * 32 + fn * 16 + lr;
                    P[(size_t)gm * C_ + c] = acc[fm][fn][r];
                }
            }
        }
    }
}

// ---------------------------------------------------------------------------
// Phase 2 — R4/R8/R9 structure, single variable: UT 5 -> 2 (8 KB writes per
// block, 102400 blocks). Final point on the granularity axis (400 KB >>
// 320 KB >> 40 KB > 20 KB so far). NT stores (R7 A/B-confirmed), chunked
// XCD swizzle (R4-confirmed). Decision rule: >=162 us -> axis exhausted,
// declare roofline at best config.
// ---------------------------------------------------------------------------
constexpr int UT_  = 2;
constexpr int NBLK = B_ * T_ * (U_ / UT_);   // 102400, divisible by 8
constexpr int NXCD = 8;

__global__ __launch_bounds__(256) void bcast_add(
    const float* __restrict__ ep, const float* __restrict__ dp,
    float* __restrict__ out)
{
    // chunked XCD swizzle (bijective: NBLK % 8 == 0)
    const int bid  = blockIdx.x;
    const int lbid = (bid & (NXCD - 1)) * (NBLK / NXCD) + (bid >> 3);

    const int ug  = lbid % (U_ / UT_);
    const int bt  = lbid / (U_ / UT_);
    const int b   = bt / T_;
    const int tid = threadIdx.x;
    const int coff = tid * 4;

    const f32x4 e = *reinterpret_cast<const f32x4*>(&ep[(size_t)bt * C_ + coff]);

    const float* dpr = dp + (size_t)(b * U_ + ug * UT_) * C_ + coff;
    float* outp = out + ((size_t)bt * U_ + ug * UT_) * C_ + coff;

    // load all dp rows first (independent -> all in flight), then add+store
    f32x4 d[UT_];
    #pragma unroll
    for (int i = 0; i < UT_; ++i)
        d[i] = *reinterpret_cast<const f32x4*>(dpr + (size_t)i * C_);

    #pragma unroll
    for (int i = 0; i < UT_; ++i) {
        const f32x4 r = e + d[i];
        __builtin_nontemporal_store(r, reinterpret_cast<f32x4*>(outp + (size_t)i * C_));
    }
}

extern "C" void kernel_launch(void* const* d_in, const int* in_sizes, int n_in,
                              void* d_out, int out_size, void* d_ws, size_t ws_size,
                              hipStream_t stream)
{
    const float* enc = (const float*)d_in[0];   // (B, T, D)
    const float* dec = (const float*)d_in[1];   // (B, U, D)
    const float* W   = (const float*)d_in[2];   // (C, 2D)
    float* out = (float*)d_out;                 // (B, T, U, C) fp32

    const int Menc = B_ * T_;   // 2048
    const int Mdec = B_ * U_;   // 400

    const size_t need = (size_t)(Menc + Mdec) * C_ * sizeof(float);  // ~9.6 MB
    if (ws_size < need) return;

    float* ep = (float*)d_ws;
    float* dp = ep + (size_t)Menc * C_;

    // Phase 1: both projections, 64x64 tiles -> 624 blocks (>=2/CU)
    proj_gemm_mfma<<<dim3(C_ / 64, 32 + 7), 256, 0, stream>>>(enc, dec, W, ep, dp);

    // Phase 2: broadcast add — UT=2 granularity probe (NT + chunked swizzle)
    bcast_add<<<NBLK, 256, 0, stream>>>(ep, dp, out);
}

// Round 11
// 146.189 us; speedup vs baseline: 1.3181x; 1.0530x over previous
//
#include <hip/hip_runtime.h>

// Problem constants: B=4, T=512, U=100, D=512, C=1024
constexpr int B_ = 4;
constexpr int T_ = 512;
constexpr int U_ = 100;
constexpr int D_ = 512;
constexpr int C_ = 1024;

typedef short  s16x8 __attribute__((ext_vector_type(8)));
typedef float  f32x4 __attribute__((ext_vector_type(4)));
typedef unsigned short u16x8 __attribute__((ext_vector_type(8)));

// fp32 -> bf16 RNE (finite inputs; no NaN handling needed)
__device__ __forceinline__ unsigned short f2bf(float f) {
    unsigned int u = __float_as_uint(f);
    return (unsigned short)((u + 0x7FFFu + ((u >> 16) & 1u)) >> 16);
}

// ---------------------------------------------------------------------------
// Fused projections via bf16 MFMA — 64x64 tiles (R8-confirmed: 624 blocks,
// >=2 co-resident/CU, ~5 us). grid.y 0..31 -> enc, 32..38 -> dec (guarded).
// ---------------------------------------------------------------------------
__global__ __launch_bounds__(256) void proj_gemm_mfma(
    const float* __restrict__ enc, const float* __restrict__ dec,
    const float* __restrict__ W, float* __restrict__ ep, float* __restrict__ dp)
{
    constexpr int BK  = 32;
    constexpr int LDK = 40;                 // 32 + 8 pad (80 B pitch)
    __shared__ unsigned short As[64 * LDK];
    __shared__ unsigned short Bs[64 * LDK];

    const int by = blockIdx.y;
    const bool is_enc = (by < 32);
    const float* __restrict__ A = is_enc ? enc : dec;
    float* __restrict__ P       = is_enc ? ep : dp;
    const int M    = is_enc ? (B_ * T_) : (B_ * U_);
    const int m0   = (is_enc ? by : (by - 32)) * 64;
    const int woff = is_enc ? 0 : D_;
    const int bn   = blockIdx.x * 64;

    const int tid  = threadIdx.x;
    const int lane = tid & 63;
    const int w    = tid >> 6;              // wave 0..3
    const int wm   = w >> 1;                // 0..1 (m half)
    const int wn   = w & 1;                 // 0..1 (n half)
    const int lr   = lane & 15;
    const int lk   = lane >> 4;             // 0..3

    // staging: 4 threads per row, 8 k-floats each
    const int srow = tid >> 2;              // 0..63
    const int sq   = tid & 3;               // k-offset 8*sq

    f32x4 acc[2][2] = {};

    const float* __restrict__ aBase = A + (size_t)(m0 + srow) * D_ + sq * 8;
    const float* __restrict__ wBase = W + (size_t)(bn + srow) * (2 * D_) + woff + sq * 8;
    const bool arow_ok = (m0 + srow) < M;

    for (int kt = 0; kt < D_ / BK; ++kt) {
        if (kt) __syncthreads();
        const int k0 = kt * BK;

        {   // stage A (guarded)
            u16x8 v = {};
            if (arow_ok) {
                const float4 f0 = *reinterpret_cast<const float4*>(aBase + k0 + 0);
                const float4 f1 = *reinterpret_cast<const float4*>(aBase + k0 + 4);
                v = u16x8{f2bf(f0.x), f2bf(f0.y), f2bf(f0.z), f2bf(f0.w),
                          f2bf(f1.x), f2bf(f1.y), f2bf(f1.z), f2bf(f1.w)};
            }
            *reinterpret_cast<u16x8*>(&As[srow * LDK + sq * 8]) = v;
        }
        {   // stage B (W rows always in range: bn+srow < 1024)
            const float4 f0 = *reinterpret_cast<const float4*>(wBase + k0 + 0);
            const float4 f1 = *reinterpret_cast<const float4*>(wBase + k0 + 4);
            const u16x8 v = {f2bf(f0.x), f2bf(f0.y), f2bf(f0.z), f2bf(f0.w),
                             f2bf(f1.x), f2bf(f1.y), f2bf(f1.z), f2bf(f1.w)};
            *reinterpret_cast<u16x8*>(&Bs[srow * LDK + sq * 8]) = v;
        }
        __syncthreads();

        s16x8 afrag[2];
        #pragma unroll
        for (int fm = 0; fm < 2; ++fm)
            afrag[fm] = *reinterpret_cast<const s16x8*>(
                &As[(wm * 32 + fm * 16 + lr) * LDK + lk * 8]);
        #pragma unroll
        for (int fn = 0; fn < 2; ++fn) {
            const s16x8 bfrag = *reinterpret_cast<const s16x8*>(
                &Bs[(wn * 32 + fn * 16 + lr) * LDK + lk * 8]);
            #pragma unroll
            for (int fm = 0; fm < 2; ++fm)
                acc[fm][fn] = __builtin_amdgcn_mfma_f32_16x16x32_bf16(
                    afrag[fm], bfrag, acc[fm][fn], 0, 0, 0);
        }
    }

    // epilogue: C/D layout col=lane&15, row=(lane>>4)*4+r
    #pragma unroll
    for (int fm = 0; fm < 2; ++fm) {
        #pragma unroll
        for (int r = 0; r < 4; ++r) {
            const int gm = m0 + wm * 32 + fm * 16 + lk * 4 + r;
            if (gm < M) {
                #pragma unroll
                for (int fn = 0; fn < 2; ++fn) {
                    const int c = bn + wn * 32 + fn * 16 + lr;
                    P[(size_t)gm * C_ + c] = acc[fm][fn][r];
                }
            }
        }
    }
}

// ---------------------------------------------------------------------------
// Phase 2 — final granularity point: UT=1 (4 KB writes/block, 204800 blocks,
// one output row per block). Curve so far: 400K(192.7) >> 320K(185.8) >>
// 40K(164.5) > 20K(162.3) > 8K(153.9) us. Mechanism: short-lived blocks in
// lbid-sequential order keep each XCD's active DRAM write span compact.
// ep L2-read volume doubles vs UT=2 (819 MB total) but L2 agg BW (34.5
// TB/s) is not binding (proven by UT=5->2 improving while doubling it).
// NT stores (R7 A/B), chunked XCD swizzle (R4). Decision rule: >=153 us ->
// restore UT=2 and declare roofline.
// ---------------------------------------------------------------------------
constexpr int UT_  = 1;
constexpr int NBLK = B_ * T_ * (U_ / UT_);   // 204800, divisible by 8
constexpr int NXCD = 8;

__global__ __launch_bounds__(256) void bcast_add(
    const float* __restrict__ ep, const float* __restrict__ dp,
    float* __restrict__ out)
{
    // chunked XCD swizzle (bijective: NBLK % 8 == 0)
    const int bid  = blockIdx.x;
    const int lbid = (bid & (NXCD - 1)) * (NBLK / NXCD) + (bid >> 3);

    const int u   = lbid % U_;
    const int bt  = lbid / U_;
    const int b   = bt / T_;
    const int coff = threadIdx.x * 4;

    const f32x4 e = *reinterpret_cast<const f32x4*>(&ep[(size_t)bt * C_ + coff]);
    const f32x4 d = *reinterpret_cast<const f32x4*>(&dp[(size_t)(b * U_ + u) * C_ + coff]);

    const f32x4 r = e + d;
    __builtin_nontemporal_store(
        r, reinterpret_cast<f32x4*>(out + ((size_t)bt * U_ + u) * C_ + coff));
}

extern "C" void kernel_launch(void* const* d_in, const int* in_sizes, int n_in,
                              void* d_out, int out_size, void* d_ws, size_t ws_size,
                              hipStream_t stream)
{
    const float* enc = (const float*)d_in[0];   // (B, T, D)
    const float* dec = (const float*)d_in[1];   // (B, U, D)
    const float* W   = (const float*)d_in[2];   // (C, 2D)
    float* out = (float*)d_out;                 // (B, T, U, C) fp32

    const int Menc = B_ * T_;   // 2048
    const int Mdec = B_ * U_;   // 400

    const size_t need = (size_t)(Menc + Mdec) * C_ * sizeof(float);  // ~9.6 MB
    if (ws_size < need) return;

    float* ep = (float*)d_ws;
    float* dp = ep + (size_t)Menc * C_;

    // Phase 1: both projections, 64x64 tiles -> 624 blocks (>=2/CU)
    proj_gemm_mfma<<<dim3(C_ / 64, 32 + 7), 256, 0, stream>>>(enc, dec, W, ep, dp);

    // Phase 2: broadcast add — UT=1, one output row per block
    bcast_add<<<NBLK, 256, 0, stream>>>(ep, dp, out);
}

// Round 12
// 144.770 us; speedup vs baseline: 1.3310x; 1.0098x over previous
//
#include <hip/hip_runtime.h>

// Problem constants: B=4, T=512, U=100, D=512, C=1024
constexpr int B_ = 4;
constexpr int T_ = 512;
constexpr int U_ = 100;
constexpr int D_ = 512;
constexpr int C_ = 1024;

typedef short  s16x8 __attribute__((ext_vector_type(8)));
typedef float  f32x4 __attribute__((ext_vector_type(4)));
typedef unsigned short u16x8 __attribute__((ext_vector_type(8)));

// fp32 -> bf16 RNE (finite inputs; no NaN handling needed)
__device__ __forceinline__ unsigned short f2bf(float f) {
    unsigned int u = __float_as_uint(f);
    return (unsigned short)((u + 0x7FFFu + ((u >> 16) & 1u)) >> 16);
}

// ---------------------------------------------------------------------------
// Fused projections via bf16 MFMA — 64x64 tiles (R8-confirmed: 624 blocks,
// >=2 co-resident/CU, ~5 us). grid.y 0..31 -> enc, 32..38 -> dec (guarded).
// ---------------------------------------------------------------------------
__global__ __launch_bounds__(256) void proj_gemm_mfma(
    const float* __restrict__ enc, const float* __restrict__ dec,
    const float* __restrict__ W, float* __restrict__ ep, float* __restrict__ dp)
{
    constexpr int BK  = 32;
    constexpr int LDK = 40;                 // 32 + 8 pad (80 B pitch)
    __shared__ unsigned short As[64 * LDK];
    __shared__ unsigned short Bs[64 * LDK];

    const int by = blockIdx.y;
    const bool is_enc = (by < 32);
    const float* __restrict__ A = is_enc ? enc : dec;
    float* __restrict__ P       = is_enc ? ep : dp;
    const int M    = is_enc ? (B_ * T_) : (B_ * U_);
    const int m0   = (is_enc ? by : (by - 32)) * 64;
    const int woff = is_enc ? 0 : D_;
    const int bn   = blockIdx.x * 64;

    const int tid  = threadIdx.x;
    const int lane = tid & 63;
    const int w    = tid >> 6;              // wave 0..3
    const int wm   = w >> 1;                // 0..1 (m half)
    const int wn   = w & 1;                 // 0..1 (n half)
    const int lr   = lane & 15;
    const int lk   = lane >> 4;             // 0..3

    // staging: 4 threads per row, 8 k-floats each
    const int srow = tid >> 2;              // 0..63
    const int sq   = tid & 3;               // k-offset 8*sq

    f32x4 acc[2][2] = {};

    const float* __restrict__ aBase = A + (size_t)(m0 + srow) * D_ + sq * 8;
    const float* __restrict__ wBase = W + (size_t)(bn + srow) * (2 * D_) + woff + sq * 8;
    const bool arow_ok = (m0 + srow) < M;

    for (int kt = 0; kt < D_ / BK; ++kt) {
        if (kt) __syncthreads();
        const int k0 = kt * BK;

        {   // stage A (guarded)
            u16x8 v = {};
            if (arow_ok) {
                const float4 f0 = *reinterpret_cast<const float4*>(aBase + k0 + 0);
                const float4 f1 = *reinterpret_cast<const float4*>(aBase + k0 + 4);
                v = u16x8{f2bf(f0.x), f2bf(f0.y), f2bf(f0.z), f2bf(f0.w),
                          f2bf(f1.x), f2bf(f1.y), f2bf(f1.z), f2bf(f1.w)};
            }
            *reinterpret_cast<u16x8*>(&As[srow * LDK + sq * 8]) = v;
        }
        {   // stage B (W rows always in range: bn+srow < 1024)
            const float4 f0 = *reinterpret_cast<const float4*>(wBase + k0 + 0);
            const float4 f1 = *reinterpret_cast<const float4*>(wBase + k0 + 4);
            const u16x8 v = {f2bf(f0.x), f2bf(f0.y), f2bf(f0.z), f2bf(f0.w),
                             f2bf(f1.x), f2bf(f1.y), f2bf(f1.z), f2bf(f1.w)};
            *reinterpret_cast<u16x8*>(&Bs[srow * LDK + sq * 8]) = v;
        }
        __syncthreads();

        s16x8 afrag[2];
        #pragma unroll
        for (int fm = 0; fm < 2; ++fm)
            afrag[fm] = *reinterpret_cast<const s16x8*>(
                &As[(wm * 32 + fm * 16 + lr) * LDK + lk * 8]);
        #pragma unroll
        for (int fn = 0; fn < 2; ++fn) {
            const s16x8 bfrag = *reinterpret_cast<const s16x8*>(
                &Bs[(wn * 32 + fn * 16 + lr) * LDK + lk * 8]);
            #pragma unroll
            for (int fm = 0; fm < 2; ++fm)
                acc[fm][fn] = __builtin_amdgcn_mfma_f32_16x16x32_bf16(
                    afrag[fm], bfrag, acc[fm][fn], 0, 0, 0);
        }
    }

    // epilogue: C/D layout col=lane&15, row=(lane>>4)*4+r
    #pragma unroll
    for (int fm = 0; fm < 2; ++fm) {
        #pragma unroll
        for (int r = 0; r < 4; ++r) {
            const int gm = m0 + wm * 32 + fm * 16 + lk * 4 + r;
            if (gm < M) {
                #pragma unroll
                for (int fn = 0; fn < 2; ++fn) {
                    const int c = bn + wn * 32 + fn * 16 + lr;
                    P[(size_t)gm * C_ + c] = acc[fm][fn][r];
                }
            }
        }
    }
}

// ---------------------------------------------------------------------------
// Phase 2 — finest granularity point: HALF-ROW blocks. 128 threads, 2 KB
// writes/block, 409600 blocks. Curve: 400K(192.7) >> 320K(185.8) >>
// 40K(164.5) > 20K(162.3) > 8K(153.9) > 4K(146.2) us — still monotone.
// Mechanism: short-lived blocks retiring in lbid-sequential order keep each
// XCD's active DRAM write span compact; finer blocks = tighter frontier.
// Opposing costs now in play: CP dispatch rate (~1.2 WG/cycle) and per-block
// setup overhead (~15 instrs vs 3 memory ops). NT stores (R7 A/B), chunked
// XCD swizzle (R4). Decision rule: >=146 us -> restore UT=1/256t, declare.
// ---------------------------------------------------------------------------
constexpr int NROW = B_ * T_ * U_;       // 204800 output rows
constexpr int NBLK = NROW * 2;           // 409600 half-row blocks, %8==0
constexpr int NXCD = 8;

__global__ __launch_bounds__(128) void bcast_add(
    const float* __restrict__ ep, const float* __restrict__ dp,
    float* __restrict__ out)
{
    // chunked XCD swizzle (bijective: NBLK % 8 == 0)
    const int bid  = blockIdx.x;
    const int lbid = (bid & (NXCD - 1)) * (NBLK / NXCD) + (bid >> 3);

    const int row  = lbid >> 1;           // output row (bt*U + u)
    const int half = lbid & 1;            // which 2 KB half
    const int u    = row % U_;
    const int bt   = row / U_;
    const int b    = bt / T_;
    const int coff = half * 512 + threadIdx.x * 4;

    const f32x4 e = *reinterpret_cast<const f32x4*>(&ep[(size_t)bt * C_ + coff]);
    const f32x4 d = *reinterpret_cast<const f32x4*>(&dp[(size_t)(b * U_ + u) * C_ + coff]);

    const f32x4 r = e + d;
    __builtin_nontemporal_store(
        r, reinterpret_cast<f32x4*>(out + (size_t)row * C_ + coff));
}

extern "C" void kernel_launch(void* const* d_in, const int* in_sizes, int n_in,
                              void* d_out, int out_size, void* d_ws, size_t ws_size,
                              hipStream_t stream)
{
    const float* enc = (const float*)d_in[0];   // (B, T, D)
    const float* dec = (const float*)d_in[1];   // (B, U, D)
    const float* W   = (const float*)d_in[2];   // (C, 2D)
    float* out = (float*)d_out;                 // (B, T, U, C) fp32

    const int Menc = B_ * T_;   // 2048
    const int Mdec = B_ * U_;   // 400

    const size_t need = (size_t)(Menc + Mdec) * C_ * sizeof(float);  // ~9.6 MB
    if (ws_size < need) return;

    float* ep = (float*)d_ws;
    float* dp = ep + (size_t)Menc * C_;

    // Phase 1: both projections, 64x64 tiles -> 624 blocks (>=2/CU)
    proj_gemm_mfma<<<dim3(C_ / 64, 32 + 7), 256, 0, stream>>>(enc, dec, W, ep, dp);

    // Phase 2: broadcast add — half-row blocks (finest granularity point)
    bcast_add<<<NBLK, 128, 0, stream>>>(ep, dp, out);
}